// Round 20
// baseline (98.217 us; speedup 1.0000x reference)
//
#include <hip/hip_runtime.h>
#include <math.h>

// ChamferLoss: pred [32,4096,3] f32, gt [32,4096,3] f32 -> scalar f32.
//
// R24 = R23 EXACTLY + T19 sched_group_barrier pinning of the inner loop.
// R23 post-mortem: T15 source-level pipelining produced IDENTICAL counters
// to R19 (48.8us, VALU 55, Mfma 27) -> the compiler canonicalizes source
// order away, sinking each fold right after its producing MFMA; the wave
// then stalls through MFMA latency every tile. Evidence of no overlap:
// VALU busy (26.8us) + MFMA busy (13.7us) + barriers ~ wall (48.7us),
// additive. An overlapped wall would be ~30-35us. SGB is the compile-time
// tool that CAN pin the interleave (m137 found it null on GEMM where the
// schedule was already good; here counters prove the schedule is the
// bottleneck -- the regime where T19's mechanism binds). Zero correctness
// risk: SGB is scheduling-only (unlike R18's asm min3, which corrupted
// via the uncovered MAI->INLINEASM hazard).
// Pin per tile: DS_READ(1) MFMA(1) VALU(20=fold a0p) MFMA(1) VALU(20).
//
// Layouts (m74/m101-verified, 32x32x16 bf16):
//   A: row = lane&31, k = 8*(lane>>5)+i
//   B: col = lane&31, k = 8*(lane>>5)+i
//   C: col = lane&31, row = (reg&3) + 8*(reg>>2) + 4*(lane>>5)
// K-slot map (A = -2*query split h/m, B = target split h/m):
//   k0-5: Ah*(Bh,Bm)  k6-11: Am*(Bh,Bm)  k12-13: Q2h,Q2m*1  k14-15: 1*T2h,T2m
//   => acc = d2 = q2 + t2 - 2*dot directly.  (absmax 0.0 in R11-R23)

typedef short short8 __attribute__((ext_vector_type(8)));
typedef float f32x16 __attribute__((ext_vector_type(16)));
typedef unsigned int uint;

#define NPTS  4096
#define TPBM  512           // 8 waves, each owns 64 rows (2 A-frags)
#define TPBP  256
#define NPANEL 8            // 512-row query panels
#define GRID_MAIN (2 * 32 * NPANEL)          // 512
#define CHT   32            // tiles per chunk (32 cols each) = 32KB staged
#define NCH   4             // 128 tiles total per (dir,batch)
#define ONEB ((short)0x3F80)                 // bf16 1.0

// LLVM SchedGroupMask (per m137): VALU=0x2, MFMA=0x8, DS_READ=0x100
#define SGB(mask, n) __builtin_amdgcn_sched_group_barrier((mask), (n), 0)

// ---- bf16 split helpers (RNE) ----
__device__ __forceinline__ unsigned short bf16h(float f) {
    uint u = __float_as_uint(f);
    uint r = u + 0x7FFFu + ((u >> 16) & 1u);
    return (unsigned short)(r >> 16);
}
__device__ __forceinline__ float bf16f(unsigned short h) {
    return __uint_as_float(((uint)h) << 16);
}
struct Split2 { unsigned short h, m; };
__device__ __forceinline__ Split2 split2(float x) {
    Split2 s;
    s.h = bf16h(x);
    s.m = bf16h(x - bf16f(s.h));
    return s;
}

// ---- main: block = (dir, batch, 512 query rows) x all 4096 target cols ----
__global__ __launch_bounds__(TPBM, 4) void chamfer_mfma(
    const float* __restrict__ pred,
    const float* __restrict__ gt,
    float* __restrict__ wsgt)
{
    const int bx    = blockIdx.x;      // 512 = dir(2) x b(32) x panel(8)
    const int dir   = bx >> 8;
    const int rem   = bx & 255;
    const int b     = rem >> 3;
    const int panel = rem & 7;
    const int tid   = threadIdx.x;
    const int lane  = tid & 63, wid = tid >> 6;
    const int c31   = lane & 31, half = lane >> 5;

    __shared__ short8 sB[CHT * 64];   // 32 KB, shared by all 8 waves
    __shared__ float  sw[8];

    // dir0: queries = gt rows, targets = pred; dir1: queries = pred, targets = gt
    const float* qsrc = (dir ? pred : gt) + (size_t)b * NPTS * 3;
    const float* tsrc = (dir ? gt : pred) + (size_t)b * NPTS * 3;

    // 2 A-frags: rows panel*512 + wid*64 + fr*32 + c31; -2*coords, q2 baked.
    short8 afr[2];
    float gm[2][16];
#pragma unroll
    for (int fr = 0; fr < 2; ++fr) {
        const int row = panel * 512 + wid * 64 + fr * 32 + c31;
        const float* ap = qsrc + (size_t)row * 3;
        float x = ap[0], y = ap[1], z = ap[2];
        Split2 X = split2(-2.0f*x), Y = split2(-2.0f*y), Z = split2(-2.0f*z);
        Split2 Q2 = split2(fmaf(x, x, fmaf(y, y, z * z)));
        short8 a;
        if (half == 0) {
            a[0]=(short)X.h; a[1]=(short)Y.h; a[2]=(short)Z.h;
            a[3]=(short)X.h; a[4]=(short)Y.h; a[5]=(short)Z.h;
            a[6]=(short)X.m; a[7]=(short)Y.m;
        } else {
            a[0]=(short)Z.m; a[1]=(short)X.m; a[2]=(short)Y.m; a[3]=(short)Z.m;
            a[4]=(short)Q2.h; a[5]=(short)Q2.m; a[6]=ONEB; a[7]=ONEB;
        }
        afr[fr] = a;
#pragma unroll
        for (int r = 0; r < 16; ++r) gm[fr][r] = 1e30f;
    }

    const f32x16 zero = {0.f,0.f,0.f,0.f,0.f,0.f,0.f,0.f,
                         0.f,0.f,0.f,0.f,0.f,0.f,0.f,0.f};

    // T14 async-stage, raw form: rx/ry/rz hold the NEXT chunk's coords.
    float rx[4], ry[4], rz[4];
#pragma unroll
    for (int ps = 0; ps < 4; ++ps) {
        const int u  = ps * TPBM + tid;
        const int pt = (u >> 6) * 32 + (u & 31);     // chunk 0
        const float* p = tsrc + (size_t)pt * 3;
        rx[ps] = p[0]; ry[ps] = p[1]; rz[ps] = p[2];
    }

    for (int ch = 0; ch < NCH; ++ch) {
        __syncthreads();   // prior chunk's reads done
        // build fragments in-register, write to LDS (fused prep)
#pragma unroll
        for (int ps = 0; ps < 4; ++ps) {
            const int u = ps * TPBM + tid;
            float x = rx[ps], y = ry[ps], z = rz[ps];
            Split2 X = split2(x), Y = split2(y), Z = split2(z);
            short8 f;
            if (((u >> 5) & 1) == 0) {
                f[0]=(short)X.h; f[1]=(short)Y.h; f[2]=(short)Z.h;
                f[3]=(short)X.m; f[4]=(short)Y.m; f[5]=(short)Z.m;
                f[6]=(short)X.h; f[7]=(short)Y.h;
            } else {
                Split2 T2 = split2(fmaf(x, x, fmaf(y, y, z * z)));
                f[0]=(short)Z.h; f[1]=(short)X.m; f[2]=(short)Y.m;
                f[3]=(short)Z.m; f[4]=ONEB; f[5]=ONEB;
                f[6]=(short)T2.h; f[7]=(short)T2.m;
            }
            sB[u] = f;
        }
        __syncthreads();   // sB visible

        const int chn = (ch + 1 < NCH) ? ch + 1 : ch;   // clamp: no overread
#pragma unroll
        for (int ps = 0; ps < 4; ++ps) {
            const int u  = ps * TPBM + tid;
            const int pt = (chn * CHT + (u >> 6)) * 32 + (u & 31);
            const float* p = tsrc + (size_t)pt * 3;
            rx[ps] = p[0]; ry[ps] = p[1]; rz[ps] = p[2];
        }

        // T15 pipeline + T19 pin: MFMA(t) issues between fold(t-1) halves.
        {
            short8 b0 = sB[lane];
            f32x16 a0p = __builtin_amdgcn_mfma_f32_32x32x16_bf16(
                afr[0], b0, zero, 0, 0, 0);
            f32x16 a1p = __builtin_amdgcn_mfma_f32_32x32x16_bf16(
                afr[1], b0, zero, 0, 0, 0);
#pragma unroll 4
            for (int t = 1; t < CHT; ++t) {
                short8 bn = sB[t * 64 + lane];
                f32x16 a0n = __builtin_amdgcn_mfma_f32_32x32x16_bf16(
                    afr[0], bn, zero, 0, 0, 0);
#pragma unroll
                for (int r = 0; r < 16; ++r)
                    gm[0][r] = fminf(gm[0][r], a0p[r]);
                f32x16 a1n = __builtin_amdgcn_mfma_f32_32x32x16_bf16(
                    afr[1], bn, zero, 0, 0, 0);
#pragma unroll
                for (int r = 0; r < 16; ++r)
                    gm[1][r] = fminf(gm[1][r], a1p[r]);
                a0p = a0n; a1p = a1n;
                // T19: force the interleave the compiler keeps undoing.
                SGB(0x100, 1);   // ds_read_b128 (next tile)
                SGB(0x8,   1);   // MFMA a0(t)
                SGB(0x2,  20);   // fold a0(t-1) VALU cluster
                SGB(0x8,   1);   // MFMA a1(t)
                SGB(0x2,  20);   // fold a1(t-1) VALU cluster
            }
#pragma unroll
            for (int r = 0; r < 16; ++r) {                // epilogue folds
                gm[0][r] = fminf(gm[0][r], a0p[r]);
                gm[1][r] = fminf(gm[1][r], a1p[r]);
            }
        }
    }

    // Epilogue: fold row-mins across the 32 target-cols (c31 lanes).
#pragma unroll
    for (int off = 1; off < 32; off <<= 1)
#pragma unroll
        for (int fr = 0; fr < 2; ++fr)
#pragma unroll
            for (int r = 0; r < 16; ++r)
                gm[fr][r] = fminf(gm[fr][r], __shfl_xor(gm[fr][r], off, 64));

    // lanes 0 and 32 hold complete mins for 2x16 disjoint rows each
    float s = 0.0f;
    if (c31 == 0) {
#pragma unroll
        for (int fr = 0; fr < 2; ++fr)
#pragma unroll
            for (int r = 0; r < 16; ++r)
                s += sqrtf(fmaxf(gm[fr][r], 1e-12f));
    }
    s += __shfl_xor(s, 32, 64);   // combine halves
    if (lane == 0) sw[wid] = s;
    __syncthreads();
    if (tid == 0)
        wsgt[bx] = sw[0]+sw[1]+sw[2]+sw[3]+sw[4]+sw[5]+sw[6]+sw[7];
}

// ---- finish: one block sums the 512 per-block partials -> out[0] ----
__global__ __launch_bounds__(TPBP) void chamfer_finish(
    const float* __restrict__ wsgt, float* __restrict__ out)
{
    __shared__ float swv[TPBP / 64];
    const int tid = threadIdx.x;

    float s = 0.0f;
#pragma unroll
    for (int r = 0; r < GRID_MAIN / TPBP; ++r)
        s += wsgt[tid + r * TPBP];

#pragma unroll
    for (int off = 32; off > 0; off >>= 1) s += __shfl_down(s, off, 64);
    const int wid = tid >> 6, lane = tid & 63;
    if (lane == 0) swv[wid] = s;
    __syncthreads();
    if (tid == 0)
        out[0] = (swv[0] + swv[1] + swv[2] + swv[3]) * (1.0f / 131072.0f);
}

extern "C" void kernel_launch(void* const* d_in, const int* in_sizes, int n_in,
                              void* d_out, int out_size, void* d_ws, size_t ws_size,
                              hipStream_t stream)
{
    const float* pred = (const float*)d_in[0];
    const float* gt   = (const float*)d_in[1];
    float* out        = (float*)d_out;
    float* wsgt       = (float*)d_ws;   // 2KB of partials

    chamfer_mfma<<<dim3(GRID_MAIN), dim3(TPBM), 0, stream>>>(pred, gt, wsgt);
    chamfer_finish<<<dim3(1), dim3(TPBP), 0, stream>>>(wsgt, out);
}